// Round 1
// 2023.355 us; speedup vs baseline: 1.4566x; 1.4566x over previous
//
#include <hip/hip_runtime.h>

// MultiHeadAttention fp32 for MI355X (gfx950).
// B=4, S=2048, D_MODEL=768, H=12, DK=64.
// d_out = [out (4*2048*768)] ++ [attn_weights (4*12*2048*2048)], fp32.
// Workspace layout (floats): Qh | Kh | Vh (each [B,H,S,64]) | AO [B,S,768] | rowsum [B,H,S]
//   -> needs 25,264,128 floats = 101.1 MB of d_ws.
//
// R1 changes vs baseline (2947 us):
//  - av_kernel: 64x64 tiles (grid 1536 vs 768), acc 4x4 (VGPR down from 168),
//    register-prefetch of next k-chunk issued before compute (T14), normalized
//    write-back moved after the barrier so stores overlap compute.
//    Theory: av was latency-bound (Occ 12%, VALU 26%, HBM 13%).
//  - QKV projections fused into one dispatch (gridDim.z=3): 1152 concurrent
//    blocks instead of 3 serial launches of 384 (1.5 blocks/CU).

#define D_MODEL 768
#define NH 12
#define DK 64
#define BATCH 4
#define SEQ 2048
#define BS (BATCH * SEQ)          // 8192 rows
#define HEADS_TOTAL (BATCH * NH)  // 48

// ---------------------------------------------------------------------------
// GEMM: C[M][N] = A[M][K] @ W[K][N] + bias[N]   (used for the output proj)
// remap=1: scatter C into head-split layout [B][H][S][DK]
// 128x128 block tile, 256 threads, 8x8 per thread, BK=16.
// ---------------------------------------------------------------------------
__global__ __launch_bounds__(256)
void gemm_bias_kernel(const float* __restrict__ A, const float* __restrict__ W,
                      const float* __restrict__ bias, float* __restrict__ C,
                      int M, int N, int K, int remap)
{
    __shared__ float As[16][136];  // transposed A tile: As[k][m]
    __shared__ float Bs[16][136];  // Bs[k][n]
    const int t  = threadIdx.x;
    const int tx = t & 15, ty = t >> 4;
    const int m0 = blockIdx.y * 128;
    const int n0 = blockIdx.x * 128;

    float acc[8][8];
#pragma unroll
    for (int i = 0; i < 8; ++i)
#pragma unroll
        for (int j = 0; j < 8; ++j) acc[i][j] = 0.f;

    for (int kt = 0; kt < K; kt += 16) {
#pragma unroll
        for (int i = 0; i < 2; ++i) {
            int L = t + i * 256;
            int m = L >> 2, kq = (L & 3) * 4;
            float4 v = *(const float4*)(A + (size_t)(m0 + m) * K + kt + kq);
            As[kq + 0][m] = v.x; As[kq + 1][m] = v.y;
            As[kq + 2][m] = v.z; As[kq + 3][m] = v.w;
        }
#pragma unroll
        for (int i = 0; i < 2; ++i) {
            int L = t + i * 256;
            int kk = L >> 5, nq = (L & 31) * 4;
            *(float4*)&Bs[kk][nq] = *(const float4*)(W + (size_t)(kt + kk) * N + n0 + nq);
        }
        __syncthreads();
#pragma unroll
        for (int kk = 0; kk < 16; ++kk) {
            float a[8], b[8];
            *(float4*)&a[0] = *(float4*)&As[kk][ty * 8];
            *(float4*)&a[4] = *(float4*)&As[kk][ty * 8 + 4];
            *(float4*)&b[0] = *(float4*)&Bs[kk][tx * 8];
            *(float4*)&b[4] = *(float4*)&Bs[kk][tx * 8 + 4];
#pragma unroll
            for (int i = 0; i < 8; ++i)
#pragma unroll
                for (int j = 0; j < 8; ++j)
                    acc[i][j] += a[i] * b[j];
        }
        __syncthreads();
    }

    float bv[8];
    *(float4*)&bv[0] = *(const float4*)(bias + n0 + tx * 8);
    *(float4*)&bv[4] = *(const float4*)(bias + n0 + tx * 8 + 4);

#pragma unroll
    for (int i = 0; i < 8; ++i) {
        int m = m0 + ty * 8 + i;
        float o[8];
#pragma unroll
        for (int j = 0; j < 8; ++j) o[j] = acc[i][j] + bv[j];
        float* dst;
        if (remap) {
            int n = n0 + tx * 8;
            int b = m >> 11, s = m & 2047, h = n >> 6, d = n & 63;
            dst = C + (((size_t)(b * NH + h)) << 17) + ((size_t)s << 6) + d;
        } else {
            dst = C + (size_t)m * N + n0 + tx * 8;
        }
        *(float4*)dst       = make_float4(o[0], o[1], o[2], o[3]);
        *(float4*)(dst + 4) = make_float4(o[4], o[5], o[6], o[7]);
    }
}

// ---------------------------------------------------------------------------
// Fused Q/K/V projection: same body as gemm_bias (remap=1 hardwired), but all
// three projections launched as one grid (blockIdx.z selects the operand set)
// so 1152 blocks run concurrently instead of 3 serial 384-block dispatches.
// ---------------------------------------------------------------------------
__global__ __launch_bounds__(256)
void qkv_gemm_kernel(const float* __restrict__ Aq, const float* __restrict__ Ak,
                     const float* __restrict__ Av,
                     const float* __restrict__ Wq, const float* __restrict__ Wk,
                     const float* __restrict__ Wv,
                     const float* __restrict__ bq, const float* __restrict__ bk,
                     const float* __restrict__ bv,
                     float* __restrict__ Cq, float* __restrict__ Ck,
                     float* __restrict__ Cv)
{
    const float* A; const float* W; const float* bias; float* C;
    if (blockIdx.z == 0)      { A = Aq; W = Wq; bias = bq; C = Cq; }
    else if (blockIdx.z == 1) { A = Ak; W = Wk; bias = bk; C = Ck; }
    else                      { A = Av; W = Wv; bias = bv; C = Cv; }

    __shared__ float As[16][136];
    __shared__ float Bs[16][136];
    const int t  = threadIdx.x;
    const int tx = t & 15, ty = t >> 4;
    const int m0 = blockIdx.y * 128;
    const int n0 = blockIdx.x * 128;

    float acc[8][8];
#pragma unroll
    for (int i = 0; i < 8; ++i)
#pragma unroll
        for (int j = 0; j < 8; ++j) acc[i][j] = 0.f;

    for (int kt = 0; kt < D_MODEL; kt += 16) {
#pragma unroll
        for (int i = 0; i < 2; ++i) {
            int L = t + i * 256;
            int m = L >> 2, kq = (L & 3) * 4;
            float4 v = *(const float4*)(A + (size_t)(m0 + m) * D_MODEL + kt + kq);
            As[kq + 0][m] = v.x; As[kq + 1][m] = v.y;
            As[kq + 2][m] = v.z; As[kq + 3][m] = v.w;
        }
#pragma unroll
        for (int i = 0; i < 2; ++i) {
            int L = t + i * 256;
            int kk = L >> 5, nq = (L & 31) * 4;
            *(float4*)&Bs[kk][nq] = *(const float4*)(W + (size_t)(kt + kk) * D_MODEL + n0 + nq);
        }
        __syncthreads();
#pragma unroll
        for (int kk = 0; kk < 16; ++kk) {
            float a[8], b[8];
            *(float4*)&a[0] = *(float4*)&As[kk][ty * 8];
            *(float4*)&a[4] = *(float4*)&As[kk][ty * 8 + 4];
            *(float4*)&b[0] = *(float4*)&Bs[kk][tx * 8];
            *(float4*)&b[4] = *(float4*)&Bs[kk][tx * 8 + 4];
#pragma unroll
            for (int i = 0; i < 8; ++i)
#pragma unroll
                for (int j = 0; j < 8; ++j)
                    acc[i][j] += a[i] * b[j];
        }
        __syncthreads();
    }

    float bvv[8];
    *(float4*)&bvv[0] = *(const float4*)(bias + n0 + tx * 8);
    *(float4*)&bvv[4] = *(const float4*)(bias + n0 + tx * 8 + 4);

#pragma unroll
    for (int i = 0; i < 8; ++i) {
        int m = m0 + ty * 8 + i;
        float o[8];
#pragma unroll
        for (int j = 0; j < 8; ++j) o[j] = acc[i][j] + bvv[j];
        int n = n0 + tx * 8;
        int b = m >> 11, s = m & 2047, h = n >> 6, d = n & 63;
        float* dst = C + (((size_t)(b * NH + h)) << 17) + ((size_t)s << 6) + d;
        *(float4*)dst       = make_float4(o[0], o[1], o[2], o[3]);
        *(float4*)(dst + 4) = make_float4(o[4], o[5], o[6], o[7]);
    }
}

// ---------------------------------------------------------------------------
// Scores: per (b,h), tile of 128 q x 128 keys. s = (Q . K)/8, e = exp(s).
// Writes UNNORMALIZED e to attn area; atomicAdd per-row sums of e.
// (12288 blocks -> machine already filled; unchanged this round.)
// ---------------------------------------------------------------------------
__global__ __launch_bounds__(256)
void scores_kernel(const float* __restrict__ Qh, const float* __restrict__ Kh,
                   float* __restrict__ attn, float* __restrict__ rowsum)
{
    __shared__ float Qs[32][132];  // transposed: Qs[kd][q]
    __shared__ float Ks[32][132];  // transposed: Ks[kd][n]
    const int t  = threadIdx.x;
    const int tx = t & 15, ty = t >> 4;
    const int bh = blockIdx.z;
    const int q0 = blockIdx.y * 128;
    const int n0 = blockIdx.x * 128;
    const float* Q  = Qh + ((size_t)bh << 17);
    const float* Kp = Kh + ((size_t)bh << 17);
    float* attnBH   = attn + ((size_t)bh << 22);

    float acc[8][8];
#pragma unroll
    for (int i = 0; i < 8; ++i)
#pragma unroll
        for (int j = 0; j < 8; ++j) acc[i][j] = 0.f;

    for (int kt = 0; kt < DK; kt += 32) {
#pragma unroll
        for (int i = 0; i < 4; ++i) {
            int L = t + i * 256;
            int r = L >> 3, c4 = (L & 7) * 4;
            float4 v = *(const float4*)(Q  + (size_t)(q0 + r) * DK + kt + c4);
            Qs[c4 + 0][r] = v.x; Qs[c4 + 1][r] = v.y;
            Qs[c4 + 2][r] = v.z; Qs[c4 + 3][r] = v.w;
            float4 w = *(const float4*)(Kp + (size_t)(n0 + r) * DK + kt + c4);
            Ks[c4 + 0][r] = w.x; Ks[c4 + 1][r] = w.y;
            Ks[c4 + 2][r] = w.z; Ks[c4 + 3][r] = w.w;
        }
        __syncthreads();
#pragma unroll
        for (int kk = 0; kk < 32; ++kk) {
            float a[8], b[8];
            *(float4*)&a[0] = *(float4*)&Qs[kk][ty * 8];
            *(float4*)&a[4] = *(float4*)&Qs[kk][ty * 8 + 4];
            *(float4*)&b[0] = *(float4*)&Ks[kk][tx * 8];
            *(float4*)&b[4] = *(float4*)&Ks[kk][tx * 8 + 4];
#pragma unroll
            for (int i = 0; i < 8; ++i)
#pragma unroll
                for (int j = 0; j < 8; ++j)
                    acc[i][j] += a[i] * b[j];
        }
        __syncthreads();
    }

    float rs[8];
#pragma unroll
    for (int i = 0; i < 8; ++i) {
        float r = 0.f;
#pragma unroll
        for (int j = 0; j < 8; ++j) {
            float e = __expf(acc[i][j] * 0.125f);
            acc[i][j] = e;
            r += e;
        }
        rs[i] = r;
        float* dst = attnBH + (size_t)(q0 + ty * 8 + i) * SEQ + n0 + tx * 8;
        *(float4*)dst       = make_float4(acc[i][0], acc[i][1], acc[i][2], acc[i][3]);
        *(float4*)(dst + 4) = make_float4(acc[i][4], acc[i][5], acc[i][6], acc[i][7]);
    }
#pragma unroll
    for (int i = 0; i < 8; ++i) {
        float r = rs[i];
        r += __shfl_xor(r, 1, 16);
        r += __shfl_xor(r, 2, 16);
        r += __shfl_xor(r, 4, 16);
        r += __shfl_xor(r, 8, 16);
        if (tx == 0)
            atomicAdd(rowsum + (size_t)bh * SEQ + q0 + ty * 8 + i, r);
    }
}

// ---------------------------------------------------------------------------
// AV v2: AO[q][d] = (sum_k e[q][k] * V[k][d]) / rowsum[q]; also rewrites the
// attn tile in-place as normalized weights.
// 64x64 tile per block -> grid (32,48)=1536 blocks (6/CU by grid), acc 4x4
// (16 regs) to keep VGPR low for occupancy. Register prefetch of the next
// k-chunk is issued BEFORE the compute phase (latency hides under 512 FMAs);
// the normalized write-back is issued after the barrier so the stores also
// overlap compute.
// ---------------------------------------------------------------------------
__global__ __launch_bounds__(256)
void av_kernel(const float* __restrict__ Vh, float* __restrict__ attn,
               const float* __restrict__ rowsum, float* __restrict__ AO)
{
    __shared__ float es[64][36];  // e tile [q][k]; stride 36: 16B-aligned rows,
                                  // ty-rows land 16 banks apart (2-way = free)
    __shared__ float Vs[32][68];  // V tile [k][d]; stride 68: 16B-aligned rows
    __shared__ float rsl[64];
    const int t  = threadIdx.x;
    const int tx = t & 15, ty = t >> 4;   // d = tx*4.., q = ty*4..
    const int bh = blockIdx.y;
    const int q0 = blockIdx.x * 64;
    const float* V = Vh + ((size_t)bh << 17);
    float* attnBH  = attn + ((size_t)bh << 22);

    if (t < 64) rsl[t] = 1.0f / rowsum[(size_t)bh * SEQ + q0 + t];

    // staging geometry (constant across chunks): each thread owns
    //   es rows {er, er+32} at col ec (32-wide chunk)
    //   V  rows {vr, vr+16} at col vc (full 64 d)
    const int er = t >> 3,  ec = (t & 7) * 4;
    const int vr = t >> 4,  vc = (t & 15) * 4;

    float* gA0 = attnBH + (size_t)(q0 + er) * SEQ + ec;
    float* gA1 = attnBH + (size_t)(q0 + er + 32) * SEQ + ec;
    const float* gV0 = V + (size_t)vr * DK + vc;
    const float* gV1 = gV0 + 16 * DK;

    // prefetch chunk 0
    float4 pe0 = *(const float4*)gA0;
    float4 pe1 = *(const float4*)gA1;
    float4 pv0 = *(const float4*)gV0;
    float4 pv1 = *(const float4*)gV1;

    float acc[4][4];
#pragma unroll
    for (int i = 0; i < 4; ++i)
#pragma unroll
        for (int j = 0; j < 4; ++j) acc[i][j] = 0.f;

    __syncthreads();  // rsl visible
    const float rinv0 = rsl[er], rinv1 = rsl[er + 32];

    for (int kt = 0; kt < SEQ; kt += 32) {
        // stage current chunk from regs into LDS
        *(float4*)&es[er][ec]      = pe0;
        *(float4*)&es[er + 32][ec] = pe1;
        *(float4*)&Vs[vr][vc]      = pv0;
        *(float4*)&Vs[vr + 16][vc] = pv1;
        __syncthreads();

        // normalized attn write-back (stores drain during compute)
        *(float4*)(gA0 + kt) = make_float4(pe0.x * rinv0, pe0.y * rinv0,
                                           pe0.z * rinv0, pe0.w * rinv0);
        *(float4*)(gA1 + kt) = make_float4(pe1.x * rinv1, pe1.y * rinv1,
                                           pe1.z * rinv1, pe1.w * rinv1);
        // issue next chunk's loads now; latency hides under the FMA loop
        if (kt + 32 < SEQ) {
            pe0 = *(const float4*)(gA0 + kt + 32);
            pe1 = *(const float4*)(gA1 + kt + 32);
            pv0 = *(const float4*)(gV0 + (size_t)(kt + 32) * DK);
            pv1 = *(const float4*)(gV1 + (size_t)(kt + 32) * DK);
        }

#pragma unroll
        for (int kk = 0; kk < 32; kk += 4) {
            float4 b0 = *(float4*)&Vs[kk + 0][tx * 4];
            float4 b1 = *(float4*)&Vs[kk + 1][tx * 4];
            float4 b2 = *(float4*)&Vs[kk + 2][tx * 4];
            float4 b3 = *(float4*)&Vs[kk + 3][tx * 4];
#pragma unroll
            for (int i = 0; i < 4; ++i) {
                float4 e = *(float4*)&es[ty * 4 + i][kk];
                acc[i][0] += e.x * b0.x + e.y * b1.x + e.z * b2.x + e.w * b3.x;
                acc[i][1] += e.x * b0.y + e.y * b1.y + e.z * b2.y + e.w * b3.y;
                acc[i][2] += e.x * b0.z + e.y * b1.z + e.z * b2.z + e.w * b3.z;
                acc[i][3] += e.x * b0.w + e.y * b1.w + e.z * b2.w + e.w * b3.w;
            }
        }
        __syncthreads();
    }

    const int b = bh / NH, h = bh % NH;
#pragma unroll
    for (int i = 0; i < 4; ++i) {
        const int q = q0 + ty * 4 + i;
        const float rr = rsl[ty * 4 + i];
        float4 o = make_float4(acc[i][0] * rr, acc[i][1] * rr,
                               acc[i][2] * rr, acc[i][3] * rr);
        *(float4*)(AO + (size_t)(b * SEQ + q) * D_MODEL + h * DK + tx * 4) = o;
    }
}

// ---------------------------------------------------------------------------
extern "C" void kernel_launch(void* const* d_in, const int* in_sizes, int n_in,
                              void* d_out, int out_size, void* d_ws, size_t ws_size,
                              hipStream_t stream)
{
    const float* q   = (const float*)d_in[0];
    const float* k   = (const float*)d_in[1];
    const float* v   = (const float*)d_in[2];
    const float* Wq  = (const float*)d_in[3];
    const float* bq  = (const float*)d_in[4];
    const float* Wk  = (const float*)d_in[5];
    const float* bk  = (const float*)d_in[6];
    const float* Wv  = (const float*)d_in[7];
    const float* bv  = (const float*)d_in[8];
    const float* Wo  = (const float*)d_in[9];
    const float* bo  = (const float*)d_in[10];

    float* out  = (float*)d_out;
    float* attn = out + (size_t)BS * D_MODEL;

    const size_t HSZ = (size_t)HEADS_TOTAL * SEQ * DK;
    float* ws     = (float*)d_ws;
    float* Qh     = ws;
    float* Kh     = ws + HSZ;
    float* Vh     = ws + 2 * HSZ;
    float* AO     = ws + 3 * HSZ;
    float* rowsum = ws + 4 * HSZ;

    hipMemsetAsync(rowsum, 0, (size_t)HEADS_TOTAL * SEQ * sizeof(float), stream);

    // fused Q/K/V projections: one dispatch, 1152 blocks
    dim3 gQKV(D_MODEL / 128, BS / 128, 3);
    qkv_gemm_kernel<<<gQKV, 256, 0, stream>>>(q, k, v, Wq, Wk, Wv,
                                              bq, bk, bv, Qh, Kh, Vh);

    scores_kernel<<<dim3(SEQ / 128, SEQ / 128, HEADS_TOTAL), 256, 0, stream>>>(Qh, Kh, attn, rowsum);
    av_kernel<<<dim3(SEQ / 64, HEADS_TOTAL), 256, 0, stream>>>(Vh, attn, rowsum, AO);

    gemm_bias_kernel<<<dim3(D_MODEL / 128, BS / 128), 256, 0, stream>>>(AO, Wo, bo, out, BS, D_MODEL, D_MODEL, 0);
}